// Round 11
// baseline (118.661 us; speedup 1.0000x reference)
//
#include <hip/hip_runtime.h>

// Problem constants
#define SEQ    2048
#define IND    768
#define NPROJ  1536      // 12 heads * 128 (q64 + k64)
#define BHN    24        // BATCH(2) * HEADS(12)
#define NEGV   1000000000000.0f

typedef __attribute__((ext_vector_type(4))) float f32x4;
typedef __attribute__((ext_vector_type(8))) short s16x8;          // 8 bf16 (MFMA operand)
typedef __attribute__((ext_vector_type(8))) unsigned short u16x8;
typedef __attribute__((ext_vector_type(4))) unsigned short u16x4;

__device__ __forceinline__ unsigned short f2bf(float f) {
  unsigned int u = __builtin_bit_cast(unsigned int, f);
  u += 0x7fffu + ((u >> 16) & 1u);   // round-to-nearest-even
  return (unsigned short)(u >> 16);
}

__device__ __forceinline__ void nt_store4(float* p, f32x4 v) {
  __builtin_nontemporal_store(v, (f32x4*)p);
}

// async global->LDS, 16B per lane; LDS dest is wave-uniform base + lane*16
#define GLOAD_LDS16(g, l)                                              \
  __builtin_amdgcn_global_load_lds(                                    \
      (const __attribute__((address_space(1))) void*)(g),              \
      (__attribute__((address_space(3))) void*)(l), 16, 0, 0)

// Stage a 128x64 bf16 tile into 1024 int4 granules; slot (row,g) holds global
// granule g ^ (row&7) (source-side XOR swizzle, linear LDS dest — rule #21).
__device__ __forceinline__ void stage128x64(const unsigned short* __restrict__ src,
                                            size_t stride, int4* lds, int tid) {
  const int w = tid >> 6, l = tid & 63;
#pragma unroll
  for (int i = 0; i < 4; ++i) {
    int gb = w * 256 + i * 64;          // wave-uniform granule base
    int G = gb + l;
    int row = G >> 3, g = G & 7;
    int cb = g ^ (row & 7);
    GLOAD_LDS16(src + (size_t)row * stride + cb * 8, lds + gb);
  }
}

// Fill one fully-tri-masked 128x128 tile (fid in [0,2880) -> bh, mt>nt tile).
__device__ __forceinline__ void fill_tile(int fid, const int* __restrict__ mask,
                                          float* __restrict__ out, int tid) {
  int bh = fid / 120;
  int t = fid - bh * 120;
  int mt = 1;
  while (t >= mt) { t -= mt; ++mt; }
  int nt = t;
  int b = bh / 12;
  int m0 = mt * 128, n0 = nt * 128;
  const float scale = 0.125f;
#pragma unroll
  for (int it = 0; it < 16; ++it) {
    int id = it * 256 + tid;           // 4096 float4 units
    int row = id >> 5, c4 = id & 31;
    int gm = m0 + row;
    float rm = (float)mask[b * SEQ + gm];
    int gn0 = n0 + c4 * 4;
    f32x4 v;
#pragma unroll
    for (int q = 0; q < 4; ++q) {
      float cm = (float)mask[b * SEQ + gn0 + q];
      v[q] = -(NEGV * ((1.f - rm) + (1.f - cm) + 1.f)) * scale;
    }
    nt_store4(out + ((size_t)bh * SEQ + gm) * SEQ + gn0, v);
  }
}

// ---------------- merged prep kernel (+512 fill tiles riding the idle BW) ----
// [0,1536): x f32->bf16 | [1536,1824): W transpose | [1824,2080): RoPE tables
// [2080,2592): fill tiles fid 0..511
__global__ __launch_bounds__(256) void k_prep(const float* __restrict__ x,
                                              const float* __restrict__ W,
                                              unsigned short* __restrict__ xb,
                                              unsigned short* __restrict__ Wt,
                                              float* __restrict__ cosT,
                                              float* __restrict__ sinT,
                                              const int* __restrict__ mask,
                                              float* __restrict__ out) {
  __shared__ float Ws[64][65];
  const int bid = blockIdx.x;
  const int tid = threadIdx.x;

  if (bid < 1536) {
    int i = (bid * 256 + tid) * 8;
    float4 a = *(const float4*)(x + i);
    float4 b = *(const float4*)(x + i + 4);
    u16x8 o;
    o[0] = f2bf(a.x); o[1] = f2bf(a.y); o[2] = f2bf(a.z); o[3] = f2bf(a.w);
    o[4] = f2bf(b.x); o[5] = f2bf(b.y); o[6] = f2bf(b.z); o[7] = f2bf(b.w);
    *(u16x8*)(xb + i) = o;
  } else if (bid < 1824) {
    int tb = bid - 1536;               // 24 n-tiles x 12 k-tiles
    int nt = tb % 24, kt = tb / 24;
    int n0 = nt * 64, k0 = kt * 64;
    int cr = tid >> 4;                 // 0..15
    int cc = (tid & 15) * 4;           // 0..60
#pragma unroll
    for (int it = 0; it < 4; ++it) {
      int kr = it * 16 + cr;
      float4 v = *(const float4*)(W + (size_t)(k0 + kr) * NPROJ + n0 + cc);
      Ws[kr][cc + 0] = v.x; Ws[kr][cc + 1] = v.y;
      Ws[kr][cc + 2] = v.z; Ws[kr][cc + 3] = v.w;
    }
    __syncthreads();
#pragma unroll
    for (int it = 0; it < 4; ++it) {
      int nl = it * 16 + cr;           // local n row
      u16x4 o;
#pragma unroll
      for (int q = 0; q < 4; ++q) o[q] = f2bf(Ws[cc + q][nl]);
      *(u16x4*)(Wt + (size_t)(n0 + nl) * IND + k0 + cc) = o;
    }
  } else if (bid < 2080) {
    int i = (bid - 1824) * 256 + tid;  // 65536
    int s = i >> 5, f = i & 31;
    float freq = exp2f(-(float)f * (13.287712379549449f / 32.0f));
    float ang = (float)s * freq;
    float sv, cv;
    sincosf(ang, &sv, &cv);
    cosT[i] = cv; sinT[i] = sv;
  } else {
    fill_tile(bid - 2080, mask, out, tid);   // fid 0..511
  }
}

// ---------------- proj GEMM + below-diagonal fill ----------------
// blocks [0,384): proj 128x128 tile; blocks [384,2752): fill fid 512..2879
// Proj uses SWAPPED operands: mfma(A=Wt, B=xb) -> lane holds 4 consecutive
// proj-cols of one seq row; RoPE pair is in-lane; 8B direct stores to Qb/Kb.
__global__ __launch_bounds__(256, 2) void k_projfill(const unsigned short* __restrict__ xb,
                                                     const unsigned short* __restrict__ Wt,
                                                     const float* __restrict__ bias,
                                                     unsigned short* __restrict__ Qb,
                                                     unsigned short* __restrict__ Kb,
                                                     const float* __restrict__ cosT,
                                                     const float* __restrict__ sinT,
                                                     const int* __restrict__ mask,
                                                     float* __restrict__ out) {
  __shared__ int4 smem2[4096];   // 64 KB: proj A dbuf (32K) | B dbuf (32K); fill unused
  const int tid = threadIdx.x;

  if (blockIdx.x >= 384) {
    fill_tile(512 + (int)blockIdx.x - 384, mask, out, tid);
    return;
  }

  // ---- proj block ----
  int4* As4 = smem2;            // [2][1024]  (xb tiles)
  int4* Bs4 = smem2 + 2048;     // [2][1024]  (Wt tiles)
  // XCD-chunked swizzle within the 384 proj blocks: 384 = 8 * 48
  const int bidl = blockIdx.x;
  const int bid = (bidl & 7) * 48 + (bidl >> 3);
  const int nt = bid % 12, mt = bid / 12;
  const int m0 = mt * 128, n0 = nt * 128;
  const int wid = tid >> 6, lane = tid & 63;
  const int wr = wid >> 1, wc = wid & 1;
  const int lr = lane & 15, kg = lane >> 4;

  f32x4 acc[4][4] = {};

  const unsigned short* Abase = xb + (size_t)m0 * IND;
  const unsigned short* Bbase = Wt + (size_t)n0 * IND;

  stage128x64(Abase, IND, As4, tid);
  stage128x64(Bbase, IND, Bs4, tid);
  __syncthreads();

  for (int kt = 0; kt < 12; ++kt) {
    int cur = kt & 1;
    if (kt < 11) {
      stage128x64(Abase + (kt + 1) * 64, IND, As4 + (cur ^ 1) * 1024, tid);
      stage128x64(Bbase + (kt + 1) * 64, IND, Bs4 + (cur ^ 1) * 1024, tid);
    }
    const int4* Ac = As4 + cur * 1024;
    const int4* Bc = Bs4 + cur * 1024;
#pragma unroll
    for (int kk = 0; kk < 2; ++kk) {
      s16x8 af[4], bfr[4];
      // A operand = Wt rows (proj cols, the wave's n range)
#pragma unroll
      for (int i = 0; i < 4; ++i) {
        int r = wc * 64 + i * 16 + lr;
        af[i] = *(const s16x8*)&Bc[r * 8 + ((kk * 4 + kg) ^ (r & 7))];
      }
      // B operand = xb rows (seq rows, the wave's m range)
#pragma unroll
      for (int j = 0; j < 4; ++j) {
        int r = wr * 64 + j * 16 + lr;
        bfr[j] = *(const s16x8*)&Ac[r * 8 + ((kk * 4 + kg) ^ (r & 7))];
      }
#pragma unroll
      for (int i = 0; i < 4; ++i)
#pragma unroll
        for (int j = 0; j < 4; ++j)
          acc[i][j] = __builtin_amdgcn_mfma_f32_16x16x32_bf16(af[i], bfr[j], acc[i][j], 0, 0, 0);
    }
    __syncthreads();
  }

  // epilogue: lane holds 4 consecutive proj-cols of one seq row.
  // bias + in-lane RoPE + direct 8B bf16 stores (no LDS, no shfl).
#pragma unroll
  for (int j = 0; j < 4; ++j) {
    int gm = m0 + wr * 64 + j * 16 + lr;      // seq-row (global m)
    int s = gm & (SEQ - 1), bb = gm >> 11;
#pragma unroll
    for (int i = 0; i < 4; ++i) {
      int col0 = n0 + wc * 64 + i * 16 + kg * 4;   // global proj col of r=0
      int d0 = col0 & 63;
      int h = col0 >> 7;
      f32x4 bi = *(const f32x4*)&bias[col0];
      int fi = s * 32 + (d0 >> 1);
      float c0 = cosT[fi],     s0 = sinT[fi];
      float c1 = cosT[fi + 1], s1 = sinT[fi + 1];
      f32x4 v = acc[i][j] + bi;
      u16x4 o;
      o[0] = f2bf(v[0] * c0 - v[1] * s0);
      o[1] = f2bf(v[1] * c0 + v[0] * s0);
      o[2] = f2bf(v[2] * c1 - v[3] * s1);
      o[3] = f2bf(v[3] * c1 + v[2] * s1);
      unsigned short* dst = ((col0 & 64) == 0) ? Qb : Kb;
      *(u16x4*)(dst + ((size_t)(bb * 12 + h) * SEQ + s) * 64 + d0) = o;
    }
  }
}

// ---------------- attention scores (upper/diagonal tiles only) ----------------
// 3264 blocks = 24 bh x 136 tiles (nt>=mt); XCD-chunked: 8 x 408 (3 bh each).
// SWAPPED operands: mfma(A=K, B=Q) -> lane holds 4 consecutive n of one m row;
// direct masked NT dwordx4 stores, no LDS epilogue, single barrier.
__global__ __launch_bounds__(256, 4) void k_attn(const unsigned short* __restrict__ Qb,
                                                 const unsigned short* __restrict__ Kb,
                                                 const int* __restrict__ mask,
                                                 float* __restrict__ out) {
  __shared__ int4 smem[2048];       // 32 KB: Qs | Ks
  int4* Qs4 = smem;
  int4* Ks4 = smem + 1024;

  const int b0 = blockIdx.x;
  const int lin = (b0 & 7) * 408 + (b0 >> 3);   // bijective: 3264 = 8*408
  int bh = lin / 136;
  int t = lin - bh * 136;
  int mt = 0;
  while (t >= 16 - mt) { t -= 16 - mt; ++mt; }
  const int nt = mt + t;
  const int b = bh / 12;
  const int tid = threadIdx.x;
  const int m0 = mt * 128, n0 = nt * 128;
  const float scale = 0.125f;

  const int wid = tid >> 6, lane = tid & 63;
  const int wr = wid >> 1, wc = wid & 1;
  const int lr = lane & 15, kg = lane >> 4;

  stage128x64(Qb + ((size_t)bh * SEQ + m0) * 64, 64, Qs4, tid);
  stage128x64(Kb + ((size_t)bh * SEQ + n0) * 64, 64, Ks4, tid);
  __syncthreads();                     // needs vmcnt: global_load_lds completion

  f32x4 acc[4][4] = {};
#pragma unroll
  for (int kk = 0; kk < 2; ++kk) {
    s16x8 af[4], bfr[4];
    // A operand = K rows (the wave's n range)
#pragma unroll
    for (int i = 0; i < 4; ++i) {
      int r = wc * 64 + i * 16 + lr;
      af[i] = *(const s16x8*)&Ks4[r * 8 + ((kk * 4 + kg) ^ (r & 7))];
    }
    // B operand = Q rows (the wave's m range)
#pragma unroll
    for (int j = 0; j < 4; ++j) {
      int r = wr * 64 + j * 16 + lr;
      bfr[j] = *(const s16x8*)&Qs4[r * 8 + ((kk * 4 + kg) ^ (r & 7))];
    }
#pragma unroll
    for (int i = 0; i < 4; ++i)
#pragma unroll
      for (int j = 0; j < 4; ++j)
        acc[i][j] = __builtin_amdgcn_mfma_f32_16x16x32_bf16(af[i], bfr[j], acc[i][j], 0, 0, 0);
  }

  // epilogue: lane holds out[gm][gn0..gn0+3] per (i,j) — direct masked stores.
#pragma unroll
  for (int j = 0; j < 4; ++j) {
    int gm = m0 + wr * 64 + j * 16 + lr;
    float rmv = (float)mask[b * SEQ + gm];
    float* orow = out + ((size_t)bh * SEQ + gm) * SEQ;
#pragma unroll
    for (int i = 0; i < 4; ++i) {
      int gn0 = n0 + wc * 64 + i * 16 + kg * 4;
      int4 cm = *(const int4*)&mask[b * SEQ + gn0];
      f32x4 v = acc[i][j];
      f32x4 o;
#pragma unroll
      for (int q = 0; q < 4; ++q) {
        int gn = gn0 + q;
        float cmv = (float)((const int*)&cm)[q];
        float pen = (1.f - rmv) + (1.f - cmv) + ((gn < gm) ? 1.f : 0.f);
        o[q] = (v[q] - NEGV * pen) * scale;
      }
      nt_store4(orow + gn0, o);
    }
  }
}

// ---------------- launcher ----------------
extern "C" void kernel_launch(void* const* d_in, const int* in_sizes, int n_in,
                              void* d_out, int out_size, void* d_ws, size_t ws_size,
                              hipStream_t stream) {
  const float* x    = (const float*)d_in[0];
  const float* W    = (const float*)d_in[1];
  const float* bias = (const float*)d_in[2];
  const int*   mask = (const int*)d_in[3];
  float* out = (float*)d_out;

  char* ws = (char*)d_ws;
  // ws layout (bytes): xb 6291456 | Wt 2359296 | Qb 6291456 | Kb 6291456 | cosT 262144 | sinT 262144
  unsigned short* xb = (unsigned short*)(ws);
  unsigned short* Wt = (unsigned short*)(ws + 6291456);
  unsigned short* Qb = (unsigned short*)(ws + 6291456 + 2359296);
  unsigned short* Kb = (unsigned short*)(ws + 6291456 + 2359296 + 6291456);
  float* cosT = (float*)(ws + 6291456 + 2359296 + 6291456 + 6291456);
  float* sinT = (float*)(ws + 6291456 + 2359296 + 6291456 + 6291456 + 262144);

  k_prep<<<2592, 256, 0, stream>>>(x, W, xb, Wt, cosT, sinT, mask, out);
  k_projfill<<<2752, 256, 0, stream>>>(xb, Wt, bias, Qb, Kb, cosT, sinT, mask, out);
  k_attn<<<3264, 256, 0, stream>>>(Qb, Kb, mask, out);
}

// Round 12
// 97.909 us; speedup vs baseline: 1.2120x; 1.2120x over previous
//
#include <hip/hip_runtime.h>

// Problem constants
#define SEQ    2048
#define IND    768
#define NPROJ  1536      // 12 heads * 128 (q64 + k64)
#define BHN    24        // BATCH(2) * HEADS(12)
#define NEGV   1000000000000.0f

// Fill-tile split across kernels: k_prep gets [0,FSPLIT), k_projfill the rest.
#define FSPLIT 1300

typedef __attribute__((ext_vector_type(4))) float f32x4;
typedef __attribute__((ext_vector_type(8))) short s16x8;          // 8 bf16 (MFMA operand)
typedef __attribute__((ext_vector_type(8))) unsigned short u16x8;
typedef __attribute__((ext_vector_type(4))) unsigned short u16x4;

__device__ __forceinline__ unsigned short f2bf(float f) {
  unsigned int u = __builtin_bit_cast(unsigned int, f);
  u += 0x7fffu + ((u >> 16) & 1u);   // round-to-nearest-even
  return (unsigned short)(u >> 16);
}

__device__ __forceinline__ void nt_store4(float* p, f32x4 v) {
  __builtin_nontemporal_store(v, (f32x4*)p);
}

// Barrier ordering LDS ops only — leaves global (NT) stores in flight.
__device__ __forceinline__ void barrier_lgkm() {
  asm volatile("s_waitcnt lgkmcnt(0)" ::: "memory");
  __builtin_amdgcn_s_barrier();
}

// async global->LDS, 16B per lane; LDS dest is wave-uniform base + lane*16
#define GLOAD_LDS16(g, l)                                              \
  __builtin_amdgcn_global_load_lds(                                    \
      (const __attribute__((address_space(1))) void*)(g),              \
      (__attribute__((address_space(3))) void*)(l), 16, 0, 0)

// Stage a 128x64 bf16 tile into 1024 int4 granules; slot (row,g) holds global
// granule g ^ (row&7) (source-side XOR swizzle, linear LDS dest — rule #21).
__device__ __forceinline__ void stage128x64(const unsigned short* __restrict__ src,
                                            size_t stride, int4* lds, int tid) {
  const int w = tid >> 6, l = tid & 63;
#pragma unroll
  for (int i = 0; i < 4; ++i) {
    int gb = w * 256 + i * 64;          // wave-uniform granule base
    int G = gb + l;
    int row = G >> 3, g = G & 7;
    int cb = g ^ (row & 7);
    GLOAD_LDS16(src + (size_t)row * stride + cb * 8, lds + gb);
  }
}

// Fill one fully-tri-masked 128x128 tile (fid in [0,2880) -> bh, mt>nt tile).
__device__ __forceinline__ void fill_tile(int fid, const int* __restrict__ mask,
                                          float* __restrict__ out, int tid) {
  int bh = fid / 120;
  int t = fid - bh * 120;
  int mt = 1;
  while (t >= mt) { t -= mt; ++mt; }
  int nt = t;
  int b = bh / 12;
  int m0 = mt * 128, n0 = nt * 128;
  const float scale = 0.125f;
#pragma unroll
  for (int it = 0; it < 16; ++it) {
    int id = it * 256 + tid;           // 4096 float4 units
    int row = id >> 5, c4 = id & 31;
    int gm = m0 + row;
    float rm = (float)mask[b * SEQ + gm];
    int gn0 = n0 + c4 * 4;
    f32x4 v;
#pragma unroll
    for (int q = 0; q < 4; ++q) {
      float cm = (float)mask[b * SEQ + gn0 + q];
      v[q] = -(NEGV * ((1.f - rm) + (1.f - cm) + 1.f)) * scale;
    }
    nt_store4(out + ((size_t)bh * SEQ + gm) * SEQ + gn0, v);
  }
}

// ---------------- merged prep kernel (+FSPLIT fill tiles riding the idle BW) --
// [0,1536): x f32->bf16 | [1536,1824): W transpose | [1824,2080): RoPE tables
// [2080,2080+FSPLIT): fill tiles fid 0..FSPLIT-1
__global__ __launch_bounds__(256) void k_prep(const float* __restrict__ x,
                                              const float* __restrict__ W,
                                              unsigned short* __restrict__ xb,
                                              unsigned short* __restrict__ Wt,
                                              float* __restrict__ cosT,
                                              float* __restrict__ sinT,
                                              const int* __restrict__ mask,
                                              float* __restrict__ out) {
  __shared__ float Ws[64][65];
  const int bid = blockIdx.x;
  const int tid = threadIdx.x;

  if (bid < 1536) {
    int i = (bid * 256 + tid) * 8;
    float4 a = *(const float4*)(x + i);
    float4 b = *(const float4*)(x + i + 4);
    u16x8 o;
    o[0] = f2bf(a.x); o[1] = f2bf(a.y); o[2] = f2bf(a.z); o[3] = f2bf(a.w);
    o[4] = f2bf(b.x); o[5] = f2bf(b.y); o[6] = f2bf(b.z); o[7] = f2bf(b.w);
    *(u16x8*)(xb + i) = o;
  } else if (bid < 1824) {
    int tb = bid - 1536;               // 24 n-tiles x 12 k-tiles
    int nt = tb % 24, kt = tb / 24;
    int n0 = nt * 64, k0 = kt * 64;
    int cr = tid >> 4;                 // 0..15
    int cc = (tid & 15) * 4;           // 0..60
#pragma unroll
    for (int it = 0; it < 4; ++it) {
      int kr = it * 16 + cr;
      float4 v = *(const float4*)(W + (size_t)(k0 + kr) * NPROJ + n0 + cc);
      Ws[kr][cc + 0] = v.x; Ws[kr][cc + 1] = v.y;
      Ws[kr][cc + 2] = v.z; Ws[kr][cc + 3] = v.w;
    }
    __syncthreads();
#pragma unroll
    for (int it = 0; it < 4; ++it) {
      int nl = it * 16 + cr;           // local n row
      u16x4 o;
#pragma unroll
      for (int q = 0; q < 4; ++q) o[q] = f2bf(Ws[cc + q][nl]);
      *(u16x4*)(Wt + (size_t)(n0 + nl) * IND + k0 + cc) = o;
    }
  } else if (bid < 2080) {
    int i = (bid - 1824) * 256 + tid;  // 65536
    int s = i >> 5, f = i & 31;
    float freq = exp2f(-(float)f * (13.287712379549449f / 32.0f));
    float ang = (float)s * freq;
    float sv, cv;
    sincosf(ang, &sv, &cv);
    cosT[i] = cv; sinT[i] = sv;
  } else {
    fill_tile(bid - 2080, mask, out, tid);   // fid 0..FSPLIT-1
  }
}

// ---------------- proj GEMM + below-diagonal fill ----------------
// blocks [0,384): proj 128x128 tile; blocks [384,...): fill fid FSPLIT..2879
__global__ __launch_bounds__(256, 2) void k_projfill(const unsigned short* __restrict__ xb,
                                                     const unsigned short* __restrict__ Wt,
                                                     const float* __restrict__ bias,
                                                     unsigned short* __restrict__ Qb,
                                                     unsigned short* __restrict__ Kb,
                                                     const float* __restrict__ cosT,
                                                     const float* __restrict__ sinT,
                                                     const int* __restrict__ mask,
                                                     float* __restrict__ out) {
  __shared__ int4 smem2[4096];   // 64 KB: proj A dbuf (32K) | B dbuf (32K); fill unused
  const int tid = threadIdx.x;

  if (blockIdx.x >= 384) {
    fill_tile(FSPLIT + (int)blockIdx.x - 384, mask, out, tid);
    return;
  }

  // ---- proj block ----
  int4* As4 = smem2;            // [2][1024]
  int4* Bs4 = smem2 + 2048;     // [2][1024]
  // XCD-chunked swizzle within the 384 proj blocks: 384 = 8 * 48
  const int bidl = blockIdx.x;
  const int bid = (bidl & 7) * 48 + (bidl >> 3);
  const int nt = bid % 12, mt = bid / 12;
  const int m0 = mt * 128, n0 = nt * 128;
  const int wid = tid >> 6, lane = tid & 63;
  const int wr = wid >> 1, wc = wid & 1;
  const int lr = lane & 15, kg = lane >> 4;

  f32x4 acc[4][4] = {};

  const unsigned short* Abase = xb + (size_t)m0 * IND;
  const unsigned short* Bbase = Wt + (size_t)n0 * IND;

  stage128x64(Abase, IND, As4, tid);
  stage128x64(Bbase, IND, Bs4, tid);
  __syncthreads();

  for (int kt = 0; kt < 12; ++kt) {
    int cur = kt & 1;
    if (kt < 11) {
      stage128x64(Abase + (kt + 1) * 64, IND, As4 + (cur ^ 1) * 1024, tid);
      stage128x64(Bbase + (kt + 1) * 64, IND, Bs4 + (cur ^ 1) * 1024, tid);
    }
    const int4* Ac = As4 + cur * 1024;
    const int4* Bc = Bs4 + cur * 1024;
#pragma unroll
    for (int kk = 0; kk < 2; ++kk) {
      s16x8 af[4], bfr[4];
#pragma unroll
      for (int i = 0; i < 4; ++i) {
        int r = wr * 64 + i * 16 + lr;
        af[i] = *(const s16x8*)&Ac[r * 8 + ((kk * 4 + kg) ^ (r & 7))];
      }
#pragma unroll
      for (int j = 0; j < 4; ++j) {
        int r = wc * 64 + j * 16 + lr;
        bfr[j] = *(const s16x8*)&Bc[r * 8 + ((kk * 4 + kg) ^ (r & 7))];
      }
#pragma unroll
      for (int i = 0; i < 4; ++i)
#pragma unroll
        for (int j = 0; j < 4; ++j)
          acc[i][j] = __builtin_amdgcn_mfma_f32_16x16x32_bf16(af[i], bfr[j], acc[i][j], 0, 0, 0);
    }
    __syncthreads();
  }

  // epilogue: bias + RoPE into LDS (bf16, granule-XOR swizzled), then
  // coalesced u16x8 stores to Qb/Kb.
  unsigned short* Cs = (unsigned short*)As4;   // 32 KB = [128][128] bf16
#pragma unroll
  for (int i = 0; i < 4; ++i) {
#pragma unroll
    for (int j = 0; j < 4; ++j) {
      int colr = wc * 64 + j * 16 + lr;        // tile-rel col 0..127
      int col = n0 + colr;
      float bcol = bias[col];
      int d = col & 63;
#pragma unroll
      for (int r = 0; r < 4; ++r) {
        int rowr = wr * 64 + i * 16 + kg * 4 + r;  // tile-rel row 0..127
        int s = (m0 + rowr) & (SEQ - 1);
        float v = acc[i][j][r] + bcol;
        float p = __shfl_xor(v, 1);              // partner column (d^1)
        int ti = s * 32 + (d >> 1);
        float cv = cosT[ti], sv = sinT[ti];
        float o = (col & 1) ? (v * cv + p * sv) : (v * cv - p * sv);
        int gs = (colr >> 3) ^ (rowr & 15);
        Cs[rowr * 128 + gs * 8 + (colr & 7)] = f2bf(o);
      }
    }
  }
  barrier_lgkm();
#pragma unroll
  for (int it = 0; it < 8; ++it) {
    int id = it * 256 + tid;          // 2048 granules
    int rowr = id >> 4, g = id & 15;
    int gs = g ^ (rowr & 15);
    u16x8 v = *(const u16x8*)&Cs[rowr * 128 + gs * 8];
    int m = m0 + rowr;
    int s = m & (SEQ - 1), bb = m >> 11;
    int colg = n0 + g * 8;
    int h = colg >> 7;
    int d0 = colg & 63;
    unsigned short* dst = ((colg & 64) == 0) ? Qb : Kb;
    *(u16x8*)(dst + ((size_t)(bb * 12 + h) * SEQ + s) * 64 + d0) = v;
  }
}

// ---------------- attention scores (upper/diagonal tiles only) ----------------
// 3264 blocks = 24 bh x 136 tiles (nt>=mt); XCD-chunked: 8 x 408 (3 bh each).
__global__ __launch_bounds__(256, 4) void k_attn(const unsigned short* __restrict__ Qb,
                                                 const unsigned short* __restrict__ Kb,
                                                 const int* __restrict__ mask,
                                                 float* __restrict__ out) {
  __shared__ int4 smem[2048];       // 32 KB: Qs | Ks, reused as Cs (64x128 f32)
  int4* Qs4 = smem;
  int4* Ks4 = smem + 1024;

  const int b0 = blockIdx.x;
  const int lin = (b0 & 7) * 408 + (b0 >> 3);   // bijective: 3264 = 8*408
  int bh = lin / 136;
  int t = lin - bh * 136;
  int mt = 0;
  while (t >= 16 - mt) { t -= 16 - mt; ++mt; }
  const int nt = mt + t;
  const int b = bh / 12;
  const int tid = threadIdx.x;
  const int m0 = mt * 128, n0 = nt * 128;
  const float scale = 0.125f;

  const int wid = tid >> 6, lane = tid & 63;
  const int wr = wid >> 1, wc = wid & 1;
  const int lr = lane & 15, kg = lane >> 4;

  stage128x64(Qb + ((size_t)bh * SEQ + m0) * 64, 64, Qs4, tid);
  stage128x64(Kb + ((size_t)bh * SEQ + n0) * 64, 64, Ks4, tid);
  __syncthreads();                     // needs vmcnt: global_load_lds completion

  f32x4 acc[4][4] = {};
#pragma unroll
  for (int kk = 0; kk < 2; ++kk) {
    s16x8 af[4], bfr[4];
#pragma unroll
    for (int i = 0; i < 4; ++i) {
      int r = wr * 64 + i * 16 + lr;
      af[i] = *(const s16x8*)&Qs4[r * 8 + ((kk * 4 + kg) ^ (r & 7))];
    }
#pragma unroll
    for (int j = 0; j < 4; ++j) {
      int r = wc * 64 + j * 16 + lr;
      bfr[j] = *(const s16x8*)&Ks4[r * 8 + ((kk * 4 + kg) ^ (r & 7))];
    }
#pragma unroll
    for (int i = 0; i < 4; ++i)
#pragma unroll
      for (int j = 0; j < 4; ++j)
        acc[i][j] = __builtin_amdgcn_mfma_f32_16x16x32_bf16(af[i], bfr[j], acc[i][j], 0, 0, 0);
  }

  // epilogue: LDS transpose (2 chunks of 64 rows), LDS-only barriers,
  // coalesced NT dwordx4 stores.
  barrier_lgkm();
  float* Cs = (float*)smem;              // [64][128] f32, granule-swizzled

#pragma unroll
  for (int c = 0; c < 2; ++c) {
    if (wr == c) {
#pragma unroll
      for (int i = 0; i < 4; ++i)
#pragma unroll
        for (int j = 0; j < 4; ++j) {
          int col = wc * 64 + j * 16 + lr;
          int g = col >> 2;
#pragma unroll
          for (int r = 0; r < 4; ++r) {
            int rl = i * 16 + kg * 4 + r;
            int gs = g ^ (rl & 7);
            Cs[rl * 128 + gs * 4 + (col & 3)] = acc[i][j][r];
          }
        }
    }
    barrier_lgkm();
#pragma unroll
    for (int it = 0; it < 8; ++it) {
      int id = it * 256 + tid;           // 2048 float4 units
      int rl = id >> 5, g = id & 31;
      int gs = g ^ (rl & 7);
      f32x4 v = *(const f32x4*)&Cs[rl * 128 + gs * 4];
      int gm = m0 + c * 64 + rl;
      int gn0 = n0 + g * 4;
      float rmv = (float)mask[b * SEQ + gm];
      int4 cm = *(const int4*)&mask[b * SEQ + gn0];
      f32x4 o;
#pragma unroll
      for (int q = 0; q < 4; ++q) {
        int gn = gn0 + q;
        float cmv = (float)((const int*)&cm)[q];
        float pen = (1.f - rmv) + (1.f - cmv) + ((gn < gm) ? 1.f : 0.f);
        o[q] = (v[q] - NEGV * pen) * scale;
      }
      nt_store4(out + ((size_t)bh * SEQ + gm) * SEQ + gn0, o);
    }
    if (c == 0) barrier_lgkm();
  }
}

// ---------------- launcher ----------------
extern "C" void kernel_launch(void* const* d_in, const int* in_sizes, int n_in,
                              void* d_out, int out_size, void* d_ws, size_t ws_size,
                              hipStream_t stream) {
  const float* x    = (const float*)d_in[0];
  const float* W    = (const float*)d_in[1];
  const float* bias = (const float*)d_in[2];
  const int*   mask = (const int*)d_in[3];
  float* out = (float*)d_out;

  char* ws = (char*)d_ws;
  // ws layout (bytes): xb 6291456 | Wt 2359296 | Qb 6291456 | Kb 6291456 | cosT 262144 | sinT 262144
  unsigned short* xb = (unsigned short*)(ws);
  unsigned short* Wt = (unsigned short*)(ws + 6291456);
  unsigned short* Qb = (unsigned short*)(ws + 6291456 + 2359296);
  unsigned short* Kb = (unsigned short*)(ws + 6291456 + 2359296 + 6291456);
  float* cosT = (float*)(ws + 6291456 + 2359296 + 6291456 + 6291456);
  float* sinT = (float*)(ws + 6291456 + 2359296 + 6291456 + 6291456 + 262144);

  k_prep<<<2080 + FSPLIT, 256, 0, stream>>>(x, W, xb, Wt, cosT, sinT, mask, out);
  k_projfill<<<384 + (2880 - FSPLIT), 256, 0, stream>>>(xb, Wt, bias, Qb, Kb, cosT, sinT, mask, out);
  k_attn<<<3264, 256, 0, stream>>>(Qb, Kb, mask, out);
}

// Round 13
// 94.673 us; speedup vs baseline: 1.2534x; 1.0342x over previous
//
#include <hip/hip_runtime.h>

// Problem constants
#define SEQ    2048
#define IND    768
#define NPROJ  1536      // 12 heads * 128 (q64 + k64)
#define BHN    24        // BATCH(2) * HEADS(12)
#define NEGV   1000000000000.0f

typedef __attribute__((ext_vector_type(4))) float f32x4;
typedef __attribute__((ext_vector_type(8))) short s16x8;          // 8 bf16 (MFMA operand)
typedef __attribute__((ext_vector_type(8))) unsigned short u16x8;
typedef __attribute__((ext_vector_type(4))) unsigned short u16x4;

__device__ __forceinline__ unsigned short f2bf(float f) {
  unsigned int u = __builtin_bit_cast(unsigned int, f);
  u += 0x7fffu + ((u >> 16) & 1u);   // round-to-nearest-even
  return (unsigned short)(u >> 16);
}

__device__ __forceinline__ void nt_store4(float* p, f32x4 v) {
  __builtin_nontemporal_store(v, (f32x4*)p);
}

// Barrier ordering LDS ops only — leaves global (NT) stores in flight.
__device__ __forceinline__ void barrier_lgkm() {
  asm volatile("s_waitcnt lgkmcnt(0)" ::: "memory");
  __builtin_amdgcn_s_barrier();
}

// async global->LDS, 16B per lane; LDS dest is wave-uniform base + lane*16
#define GLOAD_LDS16(g, l)                                              \
  __builtin_amdgcn_global_load_lds(                                    \
      (const __attribute__((address_space(1))) void*)(g),              \
      (__attribute__((address_space(3))) void*)(l), 16, 0, 0)

// Stage a 128x64 bf16 tile into 1024 int4 granules; slot (row,g) holds global
// granule g ^ (row&7) (source-side XOR swizzle, linear LDS dest — rule #21).
__device__ __forceinline__ void stage128x64(const unsigned short* __restrict__ src,
                                            size_t stride, int4* lds, int tid) {
  const int w = tid >> 6, l = tid & 63;
#pragma unroll
  for (int i = 0; i < 4; ++i) {
    int gb = w * 256 + i * 64;          // wave-uniform granule base
    int G = gb + l;
    int row = G >> 3, g = G & 7;
    int cb = g ^ (row & 7);
    GLOAD_LDS16(src + (size_t)row * stride + cb * 8, lds + gb);
  }
}

// Fill one fully-tri-masked 128x128 tile (fid in [0,2880) -> bh, mt>nt tile).
__device__ __forceinline__ void fill_tile(int fid, const int* __restrict__ mask,
                                          float* __restrict__ out, int tid) {
  int bh = fid / 120;
  int t = fid - bh * 120;
  int mt = 1;
  while (t >= mt) { t -= mt; ++mt; }
  int nt = t;
  int b = bh / 12;
  int m0 = mt * 128, n0 = nt * 128;
  const float scale = 0.125f;
#pragma unroll
  for (int it = 0; it < 16; ++it) {
    int id = it * 256 + tid;           // 4096 float4 units
    int row = id >> 5, c4 = id & 31;
    int gm = m0 + row;
    float rm = (float)mask[b * SEQ + gm];
    int gn0 = n0 + c4 * 4;
    f32x4 v;
#pragma unroll
    for (int q = 0; q < 4; ++q) {
      float cm = (float)mask[b * SEQ + gn0 + q];
      v[q] = -(NEGV * ((1.f - rm) + (1.f - cm) + 1.f)) * scale;
    }
    nt_store4(out + ((size_t)bh * SEQ + gm) * SEQ + gn0, v);
  }
}

// ---------------- merged prep kernel (+512 fill tiles riding the idle BW) ----
// [0,1536): x f32->bf16 | [1536,1824): W transpose | [1824,2080): RoPE tables
// [2080,2592): fill tiles fid 0..511
__global__ __launch_bounds__(256) void k_prep(const float* __restrict__ x,
                                              const float* __restrict__ W,
                                              unsigned short* __restrict__ xb,
                                              unsigned short* __restrict__ Wt,
                                              float* __restrict__ cosT,
                                              float* __restrict__ sinT,
                                              const int* __restrict__ mask,
                                              float* __restrict__ out) {
  __shared__ float Ws[64][65];
  const int bid = blockIdx.x;
  const int tid = threadIdx.x;

  if (bid < 1536) {
    int i = (bid * 256 + tid) * 8;
    float4 a = *(const float4*)(x + i);
    float4 b = *(const float4*)(x + i + 4);
    u16x8 o;
    o[0] = f2bf(a.x); o[1] = f2bf(a.y); o[2] = f2bf(a.z); o[3] = f2bf(a.w);
    o[4] = f2bf(b.x); o[5] = f2bf(b.y); o[6] = f2bf(b.z); o[7] = f2bf(b.w);
    *(u16x8*)(xb + i) = o;
  } else if (bid < 1824) {
    int tb = bid - 1536;               // 24 n-tiles x 12 k-tiles
    int nt = tb % 24, kt = tb / 24;
    int n0 = nt * 64, k0 = kt * 64;
    int cr = tid >> 4;                 // 0..15
    int cc = (tid & 15) * 4;           // 0..60
#pragma unroll
    for (int it = 0; it < 4; ++it) {
      int kr = it * 16 + cr;
      float4 v = *(const float4*)(W + (size_t)(k0 + kr) * NPROJ + n0 + cc);
      Ws[kr][cc + 0] = v.x; Ws[kr][cc + 1] = v.y;
      Ws[kr][cc + 2] = v.z; Ws[kr][cc + 3] = v.w;
    }
    __syncthreads();
#pragma unroll
    for (int it = 0; it < 4; ++it) {
      int nl = it * 16 + cr;           // local n row
      u16x4 o;
#pragma unroll
      for (int q = 0; q < 4; ++q) o[q] = f2bf(Ws[cc + q][nl]);
      *(u16x4*)(Wt + (size_t)(n0 + nl) * IND + k0 + cc) = o;
    }
  } else if (bid < 2080) {
    int i = (bid - 1824) * 256 + tid;  // 65536
    int s = i >> 5, f = i & 31;
    float freq = exp2f(-(float)f * (13.287712379549449f / 32.0f));
    float ang = (float)s * freq;
    float sv, cv;
    sincosf(ang, &sv, &cv);
    cosT[i] = cv; sinT[i] = sv;
  } else {
    fill_tile(bid - 2080, mask, out, tid);   // fid 0..511
  }
}

// ---------------- proj GEMM + below-diagonal fill ----------------
// blocks [0,384): proj 128x128 tile; blocks [384,2752): fill fid 512..2879
__global__ __launch_bounds__(256, 2) void k_projfill(const unsigned short* __restrict__ xb,
                                                     const unsigned short* __restrict__ Wt,
                                                     const float* __restrict__ bias,
                                                     unsigned short* __restrict__ Qb,
                                                     unsigned short* __restrict__ Kb,
                                                     const float* __restrict__ cosT,
                                                     const float* __restrict__ sinT,
                                                     const int* __restrict__ mask,
                                                     float* __restrict__ out) {
  __shared__ int4 smem2[4096];   // 64 KB: proj A dbuf (32K) | B dbuf (32K); fill unused
  const int tid = threadIdx.x;

  if (blockIdx.x >= 384) {
    fill_tile(512 + (int)blockIdx.x - 384, mask, out, tid);
    return;
  }

  // ---- proj block ----
  int4* As4 = smem2;            // [2][1024]
  int4* Bs4 = smem2 + 2048;     // [2][1024]
  // XCD-chunked swizzle within the 384 proj blocks: 384 = 8 * 48
  const int bidl = blockIdx.x;
  const int bid = (bidl & 7) * 48 + (bidl >> 3);
  const int nt = bid % 12, mt = bid / 12;
  const int m0 = mt * 128, n0 = nt * 128;
  const int wid = tid >> 6, lane = tid & 63;
  const int wr = wid >> 1, wc = wid & 1;
  const int lr = lane & 15, kg = lane >> 4;

  f32x4 acc[4][4] = {};

  const unsigned short* Abase = xb + (size_t)m0 * IND;
  const unsigned short* Bbase = Wt + (size_t)n0 * IND;

  stage128x64(Abase, IND, As4, tid);
  stage128x64(Bbase, IND, Bs4, tid);
  __syncthreads();

  for (int kt = 0; kt < 12; ++kt) {
    int cur = kt & 1;
    if (kt < 11) {
      stage128x64(Abase + (kt + 1) * 64, IND, As4 + (cur ^ 1) * 1024, tid);
      stage128x64(Bbase + (kt + 1) * 64, IND, Bs4 + (cur ^ 1) * 1024, tid);
    }
    const int4* Ac = As4 + cur * 1024;
    const int4* Bc = Bs4 + cur * 1024;
#pragma unroll
    for (int kk = 0; kk < 2; ++kk) {
      s16x8 af[4], bfr[4];
#pragma unroll
      for (int i = 0; i < 4; ++i) {
        int r = wr * 64 + i * 16 + lr;
        af[i] = *(const s16x8*)&Ac[r * 8 + ((kk * 4 + kg) ^ (r & 7))];
      }
#pragma unroll
      for (int j = 0; j < 4; ++j) {
        int r = wc * 64 + j * 16 + lr;
        bfr[j] = *(const s16x8*)&Bc[r * 8 + ((kk * 4 + kg) ^ (r & 7))];
      }
#pragma unroll
      for (int i = 0; i < 4; ++i)
#pragma unroll
        for (int j = 0; j < 4; ++j)
          acc[i][j] = __builtin_amdgcn_mfma_f32_16x16x32_bf16(af[i], bfr[j], acc[i][j], 0, 0, 0);
    }
    __syncthreads();
  }

  // epilogue: bias + RoPE into LDS (bf16, granule-XOR swizzled), then
  // coalesced u16x8 stores to Qb/Kb.
  unsigned short* Cs = (unsigned short*)As4;   // 32 KB = [128][128] bf16
#pragma unroll
  for (int i = 0; i < 4; ++i) {
#pragma unroll
    for (int j = 0; j < 4; ++j) {
      int colr = wc * 64 + j * 16 + lr;        // tile-rel col 0..127
      int col = n0 + colr;
      float bcol = bias[col];
      int d = col & 63;
#pragma unroll
      for (int r = 0; r < 4; ++r) {
        int rowr = wr * 64 + i * 16 + kg * 4 + r;  // tile-rel row 0..127
        int s = (m0 + rowr) & (SEQ - 1);
        float v = acc[i][j][r] + bcol;
        float p = __shfl_xor(v, 1);              // partner column (d^1)
        int ti = s * 32 + (d >> 1);
        float cv = cosT[ti], sv = sinT[ti];
        float o = (col & 1) ? (v * cv + p * sv) : (v * cv - p * sv);
        int gs = (colr >> 3) ^ (rowr & 15);
        Cs[rowr * 128 + gs * 8 + (colr & 7)] = f2bf(o);
      }
    }
  }
  barrier_lgkm();
#pragma unroll
  for (int it = 0; it < 8; ++it) {
    int id = it * 256 + tid;          // 2048 granules
    int rowr = id >> 4, g = id & 15;
    int gs = g ^ (rowr & 15);
    u16x8 v = *(const u16x8*)&Cs[rowr * 128 + gs * 8];
    int m = m0 + rowr;
    int s = m & (SEQ - 1), bb = m >> 11;
    int colg = n0 + g * 8;
    int h = colg >> 7;
    int d0 = colg & 63;
    unsigned short* dst = ((colg & 64) == 0) ? Qb : Kb;
    *(u16x8*)(dst + ((size_t)(bb * 12 + h) * SEQ + s) * 64 + d0) = v;
  }
}

// ---------------- attention scores (upper/diagonal tiles only) ----------------
// 3264 blocks = 24 bh x 136 tiles (nt>=mt); XCD-chunked: 8 x 408 (3 bh each).
__global__ __launch_bounds__(256, 4) void k_attn(const unsigned short* __restrict__ Qb,
                                                 const unsigned short* __restrict__ Kb,
                                                 const int* __restrict__ mask,
                                                 float* __restrict__ out) {
  __shared__ int4 smem[2048];       // 32 KB: Qs | Ks, reused as Cs (64x128 f32)
  int4* Qs4 = smem;
  int4* Ks4 = smem + 1024;

  const int b0 = blockIdx.x;
  const int lin = (b0 & 7) * 408 + (b0 >> 3);   // bijective: 3264 = 8*408
  int bh = lin / 136;
  int t = lin - bh * 136;
  int mt = 0;
  while (t >= 16 - mt) { t -= 16 - mt; ++mt; }
  const int nt = mt + t;
  const int b = bh / 12;
  const int tid = threadIdx.x;
  const int m0 = mt * 128, n0 = nt * 128;
  const float scale = 0.125f;

  const int wid = tid >> 6, lane = tid & 63;
  const int wr = wid >> 1, wc = wid & 1;
  const int lr = lane & 15, kg = lane >> 4;

  stage128x64(Qb + ((size_t)bh * SEQ + m0) * 64, 64, Qs4, tid);
  stage128x64(Kb + ((size_t)bh * SEQ + n0) * 64, 64, Ks4, tid);
  __syncthreads();                     // needs vmcnt: global_load_lds completion

  f32x4 acc[4][4] = {};
#pragma unroll
  for (int kk = 0; kk < 2; ++kk) {
    s16x8 af[4], bfr[4];
#pragma unroll
    for (int i = 0; i < 4; ++i) {
      int r = wr * 64 + i * 16 + lr;
      af[i] = *(const s16x8*)&Qs4[r * 8 + ((kk * 4 + kg) ^ (r & 7))];
    }
#pragma unroll
    for (int j = 0; j < 4; ++j) {
      int r = wc * 64 + j * 16 + lr;
      bfr[j] = *(const s16x8*)&Ks4[r * 8 + ((kk * 4 + kg) ^ (r & 7))];
    }
#pragma unroll
    for (int i = 0; i < 4; ++i)
#pragma unroll
      for (int j = 0; j < 4; ++j)
        acc[i][j] = __builtin_amdgcn_mfma_f32_16x16x32_bf16(af[i], bfr[j], acc[i][j], 0, 0, 0);
  }

  // epilogue: LDS transpose (2 chunks of 64 rows), LDS-only barriers,
  // coalesced NT dwordx4 stores.
  barrier_lgkm();
  float* Cs = (float*)smem;              // [64][128] f32, granule-swizzled

#pragma unroll
  for (int c = 0; c < 2; ++c) {
    if (wr == c) {
#pragma unroll
      for (int i = 0; i < 4; ++i)
#pragma unroll
        for (int j = 0; j < 4; ++j) {
          int col = wc * 64 + j * 16 + lr;
          int g = col >> 2;
#pragma unroll
          for (int r = 0; r < 4; ++r) {
            int rl = i * 16 + kg * 4 + r;
            int gs = g ^ (rl & 7);
            Cs[rl * 128 + gs * 4 + (col & 3)] = acc[i][j][r];
          }
        }
    }
    barrier_lgkm();
#pragma unroll
    for (int it = 0; it < 8; ++it) {
      int id = it * 256 + tid;           // 2048 float4 units
      int rl = id >> 5, g = id & 31;
      int gs = g ^ (rl & 7);
      f32x4 v = *(const f32x4*)&Cs[rl * 128 + gs * 4];
      int gm = m0 + c * 64 + rl;
      int gn0 = n0 + g * 4;
      float rmv = (float)mask[b * SEQ + gm];
      int4 cm = *(const int4*)&mask[b * SEQ + gn0];
      f32x4 o;
#pragma unroll
      for (int q = 0; q < 4; ++q) {
        int gn = gn0 + q;
        float cmv = (float)((const int*)&cm)[q];
        float pen = (1.f - rmv) + (1.f - cmv) + ((gn < gm) ? 1.f : 0.f);
        o[q] = (v[q] - NEGV * pen) * scale;
      }
      nt_store4(out + ((size_t)bh * SEQ + gm) * SEQ + gn0, o);
    }
    if (c == 0) barrier_lgkm();
  }
}

// ---------------- launcher ----------------
extern "C" void kernel_launch(void* const* d_in, const int* in_sizes, int n_in,
                              void* d_out, int out_size, void* d_ws, size_t ws_size,
                              hipStream_t stream) {
  const float* x    = (const float*)d_in[0];
  const float* W    = (const float*)d_in[1];
  const float* bias = (const float*)d_in[2];
  const int*   mask = (const int*)d_in[3];
  float* out = (float*)d_out;

  char* ws = (char*)d_ws;
  // ws layout (bytes): xb 6291456 | Wt 2359296 | Qb 6291456 | Kb 6291456 | cosT 262144 | sinT 262144
  unsigned short* xb = (unsigned short*)(ws);
  unsigned short* Wt = (unsigned short*)(ws + 6291456);
  unsigned short* Qb = (unsigned short*)(ws + 6291456 + 2359296);
  unsigned short* Kb = (unsigned short*)(ws + 6291456 + 2359296 + 6291456);
  float* cosT = (float*)(ws + 6291456 + 2359296 + 6291456 + 6291456);
  float* sinT = (float*)(ws + 6291456 + 2359296 + 6291456 + 6291456 + 262144);

  k_prep<<<2592, 256, 0, stream>>>(x, W, xb, Wt, cosT, sinT, mask, out);
  k_projfill<<<2752, 256, 0, stream>>>(xb, Wt, bias, Qb, Kb, cosT, sinT, mask, out);
  k_attn<<<3264, 256, 0, stream>>>(Qb, Kb, mask, out);
}